// Round 5
// baseline (323.731 us; speedup 1.0000x reference)
//
#include <hip/hip_runtime.h>

#define Tdim 4096
#define Bdim 8
#define Cdim 64
#define Ldim 15
#define Idim 2048   // T / STRIDE
#define OUTW 4160   // C + C*C
#define NW   8      // windows per block
#define RX   (2*NW + 27)   // 43 staged x rows
#define RXC  (2*NW + 13)   // 29 centered rows
#define NBLK (Idim / NW)   // 256 blocks per batch

// One block = NW=8 consecutive windows of one batch, 256 threads (4 waves).
//  P1: stage 43 x rows into LDS once (5.4 rows/window vs 15.5 at G=2).
//  P2: compute 29 xc rows once (3.6/window vs 8.5); mu kept at j=7,9,...,21.
//  P3: ONE WAVE OWNS ONE WINDOW (g = wid + 4*wi). Per lane: 8x8 Gram tile
//      (c0=(lane>>3)*8, d0=(lane&7)*8), 64 acc VGPRs. Reduce is wave-local
//      (butterfly shuffle) -> ZERO barriers in the window loop, so the 4
//      waves drift apart and mix LDS/VALU/store phases instead of hitting
//      each pipe in block-wide lockstep (R4 falsified the occupancy theory;
//      this attacks phase serialization + staging redundancy instead).
__global__ __launch_bounds__(256, 4) void cbp_kernel(const float* __restrict__ x,
                                                     const float* __restrict__ w1,
                                                     const float* __restrict__ w2,
                                                     float* __restrict__ out) {
    __shared__ float xbuf[RX][64];
    __shared__ float xcs[RXC][64];
    __shared__ float mus[NW][64];

    const int tid = threadIdx.x;
    const int blk = blockIdx.x;
    const int b  = blk >> 8;                  // / NBLK
    const int i0 = (blk & (NBLK - 1)) * NW;   // first window index
    const int s0 = i0 << 1;                   // STRIDE = 2

    // ---- P1: stage 43 rows, float4, zero-padded ----
    const float* xb = x + (size_t)b * (Tdim * Cdim);
    for (int v = tid; v < RX * 16; v += 256) {
        const int r  = v >> 4;
        const int c4 = (v & 15) << 2;
        const int t  = s0 - 14 + r;
        float4 val = make_float4(0.f, 0.f, 0.f, 0.f);
        if (t >= 0 && t < Tdim) val = *(const float4*)(xb + (size_t)t * Cdim + c4);
        *(float4*)(&xbuf[r][c4]) = val;
    }
    __syncthreads();

    // ---- P2: 29 unique xc rows (464 float4 tasks); mu kept at odd j in [7,21] ----
    for (int v = tid; v < RXC * 16; v += 256) {
        const int j  = v >> 4;
        const int c4 = (v & 15) << 2;
        const int t  = s0 - 7 + j;
        float4 m = make_float4(0.f, 0.f, 0.f, 0.f);
#pragma unroll
        for (int k = 0; k < Ldim; ++k) {
            const float w = w1[k];               // uniform -> s_load, hoisted
            const float4 xv = *(const float4*)(&xbuf[j + k][c4]);
            m.x = fmaf(w, xv.x, m.x);
            m.y = fmaf(w, xv.y, m.y);
            m.z = fmaf(w, xv.z, m.z);
            m.w = fmaf(w, xv.w, m.w);
        }
        const float4 xv = *(const float4*)(&xbuf[j + 7][c4]);
        float4 xc = make_float4(0.f, 0.f, 0.f, 0.f);
        if (t >= 0 && t < Tdim)
            xc = make_float4(xv.x - m.x, xv.y - m.y, xv.z - m.z, xv.w - m.w);
        *(float4*)(&xcs[j][c4]) = xc;
        if (j >= 7 && j <= 21 && (j & 1))
            *(float4*)(&mus[(j - 7) >> 1][c4]) = m;   // window positions always in-range
    }
    __syncthreads();

    // ---- P3/P4/store: barrier-free per-wave window loop ----
    const int wid  = tid >> 6;
    const int lane = tid & 63;
    const int c0 = (lane >> 3) << 3;   // 0,8,...,56
    const int d0 = (lane & 7) << 3;    // 0,8,...,56

#pragma unroll
    for (int wi = 0; wi < NW / 4; ++wi) {
        const int g = wid + (wi << 2);      // wave's window within the block
        float acc[8][8];
#pragma unroll
        for (int i = 0; i < 8; ++i)
#pragma unroll
            for (int j = 0; j < 8; ++j) acc[i][j] = 0.f;

#pragma unroll
        for (int l = 0; l < Ldim; ++l) {
            const int r = 2 * g + l;        // xc row for tap l of window g
            const float4 xcA = *(const float4*)(&xcs[r][c0]);      // 8-way bcast
            const float4 xcB = *(const float4*)(&xcs[r][c0 + 4]);
            const float4 xdA = *(const float4*)(&xcs[r][d0]);
            const float4 xdB = *(const float4*)(&xcs[r][d0 + 4]);
            const float w = w2[l];          // s_load, hoisted
            float av[8], dv[8];
            av[0] = w * xcA.x; av[1] = w * xcA.y; av[2] = w * xcA.z; av[3] = w * xcA.w;
            av[4] = w * xcB.x; av[5] = w * xcB.y; av[6] = w * xcB.z; av[7] = w * xcB.w;
            dv[0] = xdA.x; dv[1] = xdA.y; dv[2] = xdA.z; dv[3] = xdA.w;
            dv[4] = xdB.x; dv[5] = xdB.y; dv[6] = xdB.z; dv[7] = xdB.w;
#pragma unroll
            for (int i = 0; i < 8; ++i)
#pragma unroll
                for (int j = 0; j < 8; ++j) acc[i][j] = fmaf(av[i], dv[j], acc[i][j]);
        }

        // wave-local sum of squares (sigma tile + this lane's mu column)
        float ss = 0.f;
#pragma unroll
        for (int i = 0; i < 8; ++i)
#pragma unroll
            for (int j = 0; j < 8; ++j) ss = fmaf(acc[i][j], acc[i][j], ss);
        const float mv = mus[g][lane];
        ss = fmaf(mv, mv, ss);
#pragma unroll
        for (int off = 32; off; off >>= 1) ss += __shfl_xor(ss, off, 64);
        const float sc = rsqrtf(fmaxf(ss, 1e-12f));

        // stores (fire-and-forget; no barrier follows in this loop)
        float* orow = out + (size_t)(b * Idim + i0 + g) * OUTW;
        if (lane < 16) {
            float4 m4 = *(const float4*)(&mus[g][lane << 2]);
            m4.x *= sc; m4.y *= sc; m4.z *= sc; m4.w *= sc;
            *(float4*)(orow + (lane << 2)) = m4;
        }
        float* osig = orow + Cdim;
#pragma unroll
        for (int i = 0; i < 8; ++i) {
            const float4 v0 = make_float4(acc[i][0] * sc, acc[i][1] * sc,
                                          acc[i][2] * sc, acc[i][3] * sc);
            const float4 v1 = make_float4(acc[i][4] * sc, acc[i][5] * sc,
                                          acc[i][6] * sc, acc[i][7] * sc);
            *(float4*)(osig + (c0 + i) * Cdim + d0)     = v0;
            *(float4*)(osig + (c0 + i) * Cdim + d0 + 4) = v1;
        }
    }
}

extern "C" void kernel_launch(void* const* d_in, const int* in_sizes, int n_in,
                              void* d_out, int out_size, void* d_ws, size_t ws_size,
                              hipStream_t stream) {
    const float* x  = (const float*)d_in[0];
    const float* w1 = (const float*)d_in[1];
    const float* w2 = (const float*)d_in[2];
    float* out = (float*)d_out;
    cbp_kernel<<<dim3(Bdim * NBLK), dim3(256), 0, stream>>>(x, w1, w2, out);
}

// Round 6
// 281.275 us; speedup vs baseline: 1.1509x; 1.1509x over previous
//
#include <hip/hip_runtime.h>

#define Tdim 4096
#define Bdim 8
#define Cdim 64
#define Ldim 15
#define Idim 2048   // T / STRIDE
#define OUTW 4160   // C + C*C
#define G    2      // windows per block
#define RX   (2*G + 27)   // 31 staged x rows
#define RXC  (2*G + 13)   // 17 centered rows
#define NBLK (Idim / G)   // 1024 blocks per batch

typedef float v4f __attribute__((ext_vector_type(4)));

// R6 = R4 with EXACTLY ONE change: epilogue stores are nontemporal.
// Rationale: R0 (G=4,16 waves) == R4 (G=2,24 waves) to 0.07% -> kernel time is
// a memory-system floor, not structure. Hypothesis: our 273MB of normal stores
// allocate dirty L2/L3 lines behind the harness fill's still-draining 1.09GB,
// serializing on writeback capacity. NT stores bypass allocation.
// Single variable vs R4; R1's NT datapoint was confounded with +45us LDS bloat.
__global__ __launch_bounds__(256, 6) void cbp_kernel(const float* __restrict__ x,
                                                     const float* __restrict__ w1,
                                                     const float* __restrict__ w2,
                                                     float* __restrict__ out) {
    __shared__ float xbuf[RX][64];
    __shared__ float xcs[RXC][64];
    __shared__ float mus[G][64];
    __shared__ float red[4][G];

    const int tid = threadIdx.x;
    const int blk = blockIdx.x;
    const int b  = blk >> 10;            // / NBLK
    const int i0 = (blk & (NBLK - 1)) << 1;   // first window index (G=2)
    const int s0 = i0 << 1;                    // STRIDE = 2

    // ---- P1: stage 31 rows, float4, zero-padded ----
    const float* xb = x + (size_t)b * (Tdim * Cdim);
    for (int v = tid; v < RX * 16; v += 256) {
        const int r  = v >> 4;
        const int c4 = (v & 15) << 2;
        const int t  = s0 - 14 + r;
        float4 val = make_float4(0.f, 0.f, 0.f, 0.f);
        if (t >= 0 && t < Tdim) val = *(const float4*)(xb + (size_t)t * Cdim + c4);
        *(float4*)(&xbuf[r][c4]) = val;
    }
    __syncthreads();

    // ---- P2: 17 unique xc rows (272 float4 tasks); mu kept at j=7,9 ----
    for (int v = tid; v < RXC * 16; v += 256) {
        const int j  = v >> 4;
        const int c4 = (v & 15) << 2;
        const int t  = s0 - 7 + j;
        float4 m = make_float4(0.f, 0.f, 0.f, 0.f);
#pragma unroll
        for (int k = 0; k < Ldim; ++k) {
            const float w = w1[k];               // uniform -> s_load, hoisted
            const float4 xv = *(const float4*)(&xbuf[j + k][c4]);
            m.x = fmaf(w, xv.x, m.x);
            m.y = fmaf(w, xv.y, m.y);
            m.z = fmaf(w, xv.z, m.z);
            m.w = fmaf(w, xv.w, m.w);
        }
        const float4 xv = *(const float4*)(&xbuf[j + 7][c4]);
        float4 xc = make_float4(0.f, 0.f, 0.f, 0.f);
        if (t >= 0 && t < Tdim)
            xc = make_float4(xv.x - m.x, xv.y - m.y, xv.z - m.z, xv.w - m.w);
        *(float4*)(&xcs[j][c4]) = xc;
        if (j == 7 || j == 9)
            *(float4*)(&mus[(j - 7) >> 1][c4]) = m;   // always in-range (s0+2g < T)
    }
    __syncthreads();

    // ---- P3: shared-row Gram accumulation (32 acc VGPRs) ----
    const int c0 = (tid >> 4) << 2;   // 0..60
    const int d0 = (tid & 15) << 2;   // 0..60
    float acc[G][4][4];
#pragma unroll
    for (int g = 0; g < G; ++g)
#pragma unroll
        for (int cc = 0; cc < 4; ++cc)
#pragma unroll
            for (int dd = 0; dd < 4; ++dd) acc[g][cc][dd] = 0.f;

#pragma unroll
    for (int r = 0; r < RXC; ++r) {
        const float4 xd = *(const float4*)(&xcs[r][d0]);   // ds_read_b128
        const float4 xc = *(const float4*)(&xcs[r][c0]);   // ds_read_b128 (bcast)
#pragma unroll
        for (int g = 0; g < G; ++g) {
            const int l = r - 2 * g;
            if (l >= 0 && l < Ldim) {                       // static after unroll
                const float w  = w2[l];                     // s_load, hoisted
                const float a0 = w * xc.x, a1 = w * xc.y, a2 = w * xc.z, a3 = w * xc.w;
                acc[g][0][0] = fmaf(a0, xd.x, acc[g][0][0]);
                acc[g][0][1] = fmaf(a0, xd.y, acc[g][0][1]);
                acc[g][0][2] = fmaf(a0, xd.z, acc[g][0][2]);
                acc[g][0][3] = fmaf(a0, xd.w, acc[g][0][3]);
                acc[g][1][0] = fmaf(a1, xd.x, acc[g][1][0]);
                acc[g][1][1] = fmaf(a1, xd.y, acc[g][1][1]);
                acc[g][1][2] = fmaf(a1, xd.z, acc[g][1][2]);
                acc[g][1][3] = fmaf(a1, xd.w, acc[g][1][3]);
                acc[g][2][0] = fmaf(a2, xd.x, acc[g][2][0]);
                acc[g][2][1] = fmaf(a2, xd.y, acc[g][2][1]);
                acc[g][2][2] = fmaf(a2, xd.z, acc[g][2][2]);
                acc[g][2][3] = fmaf(a2, xd.w, acc[g][2][3]);
                acc[g][3][0] = fmaf(a3, xd.x, acc[g][3][0]);
                acc[g][3][1] = fmaf(a3, xd.y, acc[g][3][1]);
                acc[g][3][2] = fmaf(a3, xd.z, acc[g][3][2]);
                acc[g][3][3] = fmaf(a3, xd.w, acc[g][3][3]);
            }
        }
    }

    // ---- P4: per-window sum of squares, SINGLE barrier ----
    float local[G];
#pragma unroll
    for (int g = 0; g < G; ++g) {
        float s = 0.f;
#pragma unroll
        for (int cc = 0; cc < 4; ++cc)
#pragma unroll
            for (int dd = 0; dd < 4; ++dd) s = fmaf(acc[g][cc][dd], acc[g][cc][dd], s);
        local[g] = s;
    }
    if (tid < Cdim) {
#pragma unroll
        for (int g = 0; g < G; ++g) local[g] = fmaf(mus[g][tid], mus[g][tid], local[g]);
    }
#pragma unroll
    for (int off = 32; off; off >>= 1)
#pragma unroll
        for (int g = 0; g < G; ++g) local[g] += __shfl_down(local[g], off, 64);
    if ((tid & 63) == 0) {
        const int w = tid >> 6;
#pragma unroll
        for (int g = 0; g < G; ++g) red[w][g] = local[g];
    }
    __syncthreads();

    float scale[G];
#pragma unroll
    for (int g = 0; g < G; ++g) {
        const float ss = red[0][g] + red[1][g] + red[2][g] + red[3][g];  // broadcast
        scale[g] = rsqrtf(fmaxf(ss, 1e-12f));
    }

    // ---- Epilogue: coalesced NONTEMPORAL stores (the single change vs R4) ----
#pragma unroll
    for (int g = 0; g < G; ++g) {
        const float sc = scale[g];
        float* orow = out + (size_t)(b * Idim + i0 + g) * OUTW;
        if (tid < 16) {
            const float4 m4 = *(const float4*)(&mus[g][tid << 2]);
            v4f mv = { m4.x * sc, m4.y * sc, m4.z * sc, m4.w * sc };
            __builtin_nontemporal_store(mv, (v4f*)(orow + (tid << 2)));
        }
        float* osig = orow + Cdim;
#pragma unroll
        for (int cc = 0; cc < 4; ++cc) {
            v4f v = { acc[g][cc][0] * sc, acc[g][cc][1] * sc,
                      acc[g][cc][2] * sc, acc[g][cc][3] * sc };
            __builtin_nontemporal_store(v, (v4f*)(osig + (c0 + cc) * Cdim + d0));
        }
    }
}

extern "C" void kernel_launch(void* const* d_in, const int* in_sizes, int n_in,
                              void* d_out, int out_size, void* d_ws, size_t ws_size,
                              hipStream_t stream) {
    const float* x  = (const float*)d_in[0];
    const float* w1 = (const float*)d_in[1];
    const float* w2 = (const float*)d_in[2];
    float* out = (float*)d_out;
    cbp_kernel<<<dim3(Bdim * NBLK), dim3(256), 0, stream>>>(x, w1, w2, out);
}